// Round 7
// baseline (388.160 us; speedup 1.0000x reference)
//
#include <hip/hip_runtime.h>
#include <type_traits>

#define N 4096
#define TILE 64
#define HALO 8
#define SDIM 80            // TILE + 2*HALO staging rows/cols
#define S4   20            // float4 per staged row
#define LSTR 84            // padded LDS row stride (words); 84 % 32 = 20 -> bank period 8
#define NSTEPS 8
#define GH 7               // rows per thread strip

// 8 fused cross-stencil iterations, single LDS buffer.
// Per step: read 9-row strip into regs -> barrier -> compute+write 7 rows -> barrier.
// Deferred 0.25 scaling (pure adds); one 2^-64 multiply in the final epilogue.
template <int FUSE>
__global__ __launch_bounds__(256, 2) void stencil8(const float* __restrict__ src,
                                                   float* __restrict__ dst,
                                                   const float* __restrict__ xin,
                                                   const float* __restrict__ nrm) {
    __shared__ float lds[SDIM * LSTR];   // 26.88 KB
    const int bx = blockIdx.x, by = blockIdx.y;
    const int gi0 = by * TILE - HALO;
    const int gj0 = bx * TILE - HALO;
    const int tid = threadIdx.x;
    const bool edgeBlk = (bx == 0) | (by == 0) | (bx == (N / TILE - 1)) | (by == (N / TILE - 1));

    // ---- stage 80x80 into LDS (fast path: no clamping needed) ----
    if (!edgeBlk) {
        for (int idx = tid; idx < SDIM * S4; idx += 256) {
            const int r  = idx / S4;
            const int j4 = idx - r * S4;
            const float4 v = *(const float4*)(src + (size_t)(gi0 + r) * N + gj0 + 4 * j4);
            *(float4*)&lds[r * LSTR + 4 * j4] = v;
        }
    } else {
        for (int idx = tid; idx < SDIM * S4; idx += 256) {
            const int r  = idx / S4;
            const int j4 = idx - r * S4;
            int gr = gi0 + r;
            gr = gr < 0 ? 0 : (gr > N - 1 ? N - 1 : gr);
            const int gj = gj0 + 4 * j4;
            float4 v;
            if (gj >= 0 && gj + 3 <= N - 1) {
                v = *(const float4*)(src + (size_t)gr * N + gj);
            } else {
                const float* row = src + (size_t)gr * N;
                const int c0 = min(max(gj + 0, 0), N - 1);
                const int c1 = min(max(gj + 1, 0), N - 1);
                const int c2 = min(max(gj + 2, 0), N - 1);
                const int c3 = min(max(gj + 3, 0), N - 1);
                v = make_float4(row[c0], row[c1], row[c2], row[c3]);
            }
            *(float4*)&lds[r * LSTR + 4 * j4] = v;
        }
    }
    // zero the 4 pad words of every row (keeps out-of-tile scalar reads finite)
    for (int r = tid; r < SDIM; r += 256) {
        lds[r * LSTR + 80] = 0.f; lds[r * LSTR + 81] = 0.f;
        lds[r * LSTR + 82] = 0.f; lds[r * LSTR + 83] = 0.f;
    }
    __syncthreads();

    // ---- strip mapping: thread owns rows r0..r0+6 at float4 column j4 ----
    const int g   = tid / S4;            // 0..12
    const int j4v = tid - g * S4;        // 0..19
    const int r0  = 1 + g * GH;          // 1,8,...,78
    const int j   = 4 * j4v;
    const bool active = (g < 12);        // covers rows 1..78

    const int gjx = gj0 + j;
    const bool lcl = (gjx == 0);
    const bool rcl = (gjx + 3 == N - 1);

    auto steps = [&](auto EDGEC) {
        for (int p = 0; p < NSTEPS; ++p) {
            const int s = p + 1;                 // valid region rows [s, SDIM-s)
            float4 rowv[GH + 2];
            float  lf[GH], rg[GH];
            if (active) {
#pragma unroll
                for (int k = 0; k < GH + 2; ++k) {
                    int rr = r0 - 1 + k;
                    rr = rr > SDIM - 1 ? SDIM - 1 : rr;
                    rowv[k] = *(const float4*)&lds[rr * LSTR + j];
                }
#pragma unroll
                for (int k = 0; k < GH; ++k) {
                    int rr = r0 + k;
                    rr = rr > SDIM - 2 ? SDIM - 2 : rr;
                    lf[k] = lds[rr * LSTR + j - 1];   // j=0: reads prev row's zeroed pad
                    rg[k] = lds[rr * LSTR + j + 4];   // j4=19: reads this row's zeroed pad
                }
            }
            __syncthreads();
            if (active) {
#pragma unroll
                for (int k = 0; k < GH; ++k) {
                    const int r = r0 + k;
                    if (r > SDIM - 2) break;
                    if (r < s || r >= SDIM - s) continue;   // row pyramid
                    float4 up  = rowv[k];
                    float4 cur = rowv[k + 1];
                    float4 dn  = rowv[k + 2];
                    float  lft = lf[k];
                    float  rgt = rg[k];
                    if constexpr (decltype(EDGEC)::value) {
                        const int gr = gi0 + r;
                        if (gr == 0)     up = cur;
                        if (gr == N - 1) dn = cur;
                        if (lcl) lft = cur.x;
                        if (rcl) rgt = cur.w;
                    }
                    float4 o;
                    o.x = (up.x + dn.x) + (lft   + cur.y);
                    o.y = (up.y + dn.y) + (cur.x + cur.z);
                    o.z = (up.z + dn.z) + (cur.y + cur.w);
                    o.w = (up.w + dn.w) + (cur.z + rgt);
                    *(float4*)&lds[r * LSTR + j] = o;
                }
            }
            __syncthreads();
        }
    };
    if (edgeBlk) steps(std::true_type{});
    else         steps(std::false_type{});

    // ---- store interior 64x64 ----
    const float SC = 0x1p-64f;  // undo 32 deferred 0.25 factors
    const float L0 = 0.7053f, L1 = -0.7053f, L2 = 0.7053f;
    for (int idx = tid; idx < TILE * TILE / 4; idx += 256) {
        const int rr  = idx >> 4;
        const int jj4 = idx & 15;
        const size_t base = (size_t)(by * TILE + rr) * N + bx * TILE + 4 * jj4;
        const float4 v = *(const float4*)&lds[(HALO + rr) * LSTR + HALO + 4 * jj4];
        if (FUSE) {
            const float4 h  = *(const float4*)(xin + base);
            const float4 n0 = *(const float4*)(nrm + base);
            const float4 n1 = *(const float4*)(nrm + (size_t)N * N + base);
            const float4 n2 = *(const float4*)(nrm + 2 * (size_t)N * N + base);
            float4 o;
            {
                float ao = 1.0f - fminf(fmaxf((v.x * SC - h.x) * 4.0f, 0.0f), 1.0f);
                float d1 = fmaxf(n0.x * L0 + n1.x * L1 + n2.x * L2, 0.0f);
                o.x = (d1 * 0.3f + 0.7f) * ao;
            }
            {
                float ao = 1.0f - fminf(fmaxf((v.y * SC - h.y) * 4.0f, 0.0f), 1.0f);
                float d1 = fmaxf(n0.y * L0 + n1.y * L1 + n2.y * L2, 0.0f);
                o.y = (d1 * 0.3f + 0.7f) * ao;
            }
            {
                float ao = 1.0f - fminf(fmaxf((v.z * SC - h.z) * 4.0f, 0.0f), 1.0f);
                float d1 = fmaxf(n0.z * L0 + n1.z * L1 + n2.z * L2, 0.0f);
                o.z = (d1 * 0.3f + 0.7f) * ao;
            }
            {
                float ao = 1.0f - fminf(fmaxf((v.w * SC - h.w) * 4.0f, 0.0f), 1.0f);
                float d1 = fmaxf(n0.w * L0 + n1.w * L1 + n2.w * L2, 0.0f);
                o.w = (d1 * 0.3f + 0.7f) * ao;
            }
            *(float4*)(dst + base) = o;
        } else {
            *(float4*)(dst + base) = v;
        }
    }
}

extern "C" void kernel_launch(void* const* d_in, const int* in_sizes, int n_in,
                              void* d_out, int out_size, void* d_ws, size_t ws_size,
                              hipStream_t stream) {
    const float* x       = (const float*)d_in[0];
    const float* normals = (const float*)d_in[1];
    float* out = (float*)d_out;
    float* ws  = (float*)d_ws;

    dim3 grid(N / TILE, N / TILE);
    dim3 block(256);

    // 32 iterations = 4 passes x 8 fused steps
    stencil8<0><<<grid, block, 0, stream>>>(x,   ws,  nullptr, nullptr);
    stencil8<0><<<grid, block, 0, stream>>>(ws,  out, nullptr, nullptr);
    stencil8<0><<<grid, block, 0, stream>>>(out, ws,  nullptr, nullptr);
    // final pass: 8 steps + fused AO/diffuse epilogue
    stencil8<1><<<grid, block, 0, stream>>>(ws,  out, x, normals);
}

// Round 8
// 312.999 us; speedup vs baseline: 1.2401x; 1.2401x over previous
//
#include <hip/hip_runtime.h>
#include <type_traits>

#define N 4096
#define TILE 96            // output tile per block
#define HALO 16            // halo for 16 fused steps
#define SDIM 128           // staged rows/cols = TILE + 2*HALO
#define NSTRIP 16          // row strips per block
#define GH 8               // rows per strip (register-resident)
#define NSTEPS 16          // stencil iterations fused per pass
#define NB 43              // ceil(4096/96)

// 16 fused cross-stencil iterations, register-resident row strips.
// Thread (g=tid/32, j4=tid%32) owns rows r0..r0+7 (r0=1+8g) at cols 4*j4..4*j4+3.
// Horizontal neighbors via __shfl (32 lanes/row => wave/row boundaries coincide
// with staging-edge cols, which are outside the valid trapezoid).
// LDS holds only strip-boundary rows (first/last per strip), single-buffered
// with read -> barrier -> compute -> publish -> barrier per step.
// Deferred 0.25 scaling (pure adds); one 2^-64 multiply in the final epilogue.
template <int FUSE>
__global__ __launch_bounds__(512, 4) void stencil16(const float* __restrict__ src,
                                                    float* __restrict__ dst,
                                                    const float* __restrict__ xin,
                                                    const float* __restrict__ nrm) {
    __shared__ float bnd[2][NSTRIP][SDIM];   // [0]=first row (r0), [1]=last row (r0+7); 16 KB
    const int bx = blockIdx.x, by = blockIdx.y;
    const int gi0 = by * TILE - HALO;
    const int gj0 = bx * TILE - HALO;
    const int tid = (int)threadIdx.x;
    const int g   = tid >> 5;          // strip 0..15
    const int j4  = tid & 31;          // float4 column 0..31
    const int jc  = 4 * j4;            // local col of .x
    const int r0  = 1 + g * GH;        // first owned row
    const bool edge = (bx == 0) | (by == 0) | (bx == NB - 1) | (by == NB - 1);

    float4 rows[GH];
    float4 row0 = make_float4(0.f, 0.f, 0.f, 0.f);   // g==0: staged local row 0 (static)

    // ---- stage strip into registers ----
    if (!edge) {
        const float* base = src + (size_t)(gi0 + r0) * N + (gj0 + jc);
#pragma unroll
        for (int k = 0; k < GH; ++k)
            rows[k] = *(const float4*)(base + (size_t)k * N);
        if (g == 0) row0 = *(const float4*)(src + (size_t)gi0 * N + (gj0 + jc));
    } else {
        auto ld = [&](int r) -> float4 {
            int gr = gi0 + r;
            gr = gr < 0 ? 0 : (gr > N - 1 ? N - 1 : gr);
            const int gc = gj0 + jc;
            if (gc >= 0 && gc + 3 <= N - 1)
                return *(const float4*)(src + (size_t)gr * N + gc);
            const float* row = src + (size_t)gr * N;
            return make_float4(row[min(max(gc + 0, 0), N - 1)],
                               row[min(max(gc + 1, 0), N - 1)],
                               row[min(max(gc + 2, 0), N - 1)],
                               row[min(max(gc + 3, 0), N - 1)]);
        };
#pragma unroll
        for (int k = 0; k < GH; ++k) rows[k] = ld(r0 + k);
        if (g == 0) row0 = ld(0);
    }

    const int gc0 = gj0 + jc;
    const bool lcl = edge && (gc0 == 0);
    const bool rcl = edge && (gc0 + 3 == N - 1);

    // initial boundary publish
    *(float4*)&bnd[0][g][jc] = rows[0];
    *(float4*)&bnd[1][g][jc] = rows[GH - 1];
    __syncthreads();

    auto run = [&](auto EC) {
#pragma unroll 1
        for (int p = 0; p < NSTEPS; ++p) {
            const int s = p + 1;                       // valid rows/cols [s, SDIM-s)
            // read neighbor boundary rows (prev-step values)
            float4 up_b = (g > 0) ? *(const float4*)&bnd[1][g - 1][jc] : row0;
            float4 dn_b = (g < NSTRIP - 1) ? *(const float4*)&bnd[0][g + 1][jc] : rows[GH - 1];
            __syncthreads();                           // all reads done before republish
            float4 prev = up_b;
#pragma unroll
            for (int k = 0; k < GH; ++k) {
                const int r = r0 + k;
                const float4 cur = rows[k];
                const float4 nxt = (k < GH - 1) ? rows[k + 1] : dn_b;
                if (r >= s && r < SDIM - s) {          // uniform per 32-lane group
                    float lft = __shfl_up(cur.w, 1);   // lane-1's .w = col jc-1
                    float rgt = __shfl_down(cur.x, 1); // lane+1's .x = col jc+4
                    float4 up = prev, dn = nxt;
                    if constexpr (decltype(EC)::value) {
                        const int gr = gi0 + r;
                        if (gr == 0)     up = cur;     // global edge replication
                        if (gr == N - 1) dn = cur;
                        if (lcl) lft = cur.x;
                        if (rcl) rgt = cur.w;
                    }
                    float4 o;
                    o.x = (up.x + dn.x) + (lft   + cur.y);
                    o.y = (up.y + dn.y) + (cur.x + cur.z);
                    o.z = (up.z + dn.z) + (cur.y + cur.w);
                    o.w = (up.w + dn.w) + (cur.z + rgt);
                    rows[k] = o;
                }
                prev = cur;
            }
            // publish new boundary rows
            *(float4*)&bnd[0][g][jc] = rows[0];
            *(float4*)&bnd[1][g][jc] = rows[GH - 1];
            __syncthreads();
        }
    };
    if (edge) run(std::true_type{});
    else      run(std::false_type{});

    // ---- store interior [HALO, SDIM-HALO)^2, straight from registers ----
    const float SC = 0x1p-64f;   // undo 32 deferred 0.25 factors (applied once, pass 2)
    const float L0 = 0.7053f, L1 = -0.7053f, L2 = 0.7053f;
    const bool colok = (j4 >= HALO / 4) && (j4 < (SDIM - HALO) / 4) &&
                       (!edge || gc0 + 3 <= N - 1);
    if (colok) {
#pragma unroll
        for (int k = 0; k < GH; ++k) {
            const int r = r0 + k;
            if (r < HALO || r >= SDIM - HALO) continue;
            const int gr = gi0 + r;
            if (edge && gr >= N) continue;
            const size_t base = (size_t)gr * N + gc0;
            const float4 v = rows[k];
            if constexpr (FUSE) {
                const float4 h  = *(const float4*)(xin + base);
                const float4 n0 = *(const float4*)(nrm + base);
                const float4 n1 = *(const float4*)(nrm + (size_t)N * N + base);
                const float4 n2 = *(const float4*)(nrm + 2 * (size_t)N * N + base);
                float4 o;
                {
                    float ao = 1.0f - fminf(fmaxf((v.x * SC - h.x) * 4.0f, 0.0f), 1.0f);
                    float d1 = fmaxf(n0.x * L0 + n1.x * L1 + n2.x * L2, 0.0f);
                    o.x = (d1 * 0.3f + 0.7f) * ao;
                }
                {
                    float ao = 1.0f - fminf(fmaxf((v.y * SC - h.y) * 4.0f, 0.0f), 1.0f);
                    float d1 = fmaxf(n0.y * L0 + n1.y * L1 + n2.y * L2, 0.0f);
                    o.y = (d1 * 0.3f + 0.7f) * ao;
                }
                {
                    float ao = 1.0f - fminf(fmaxf((v.z * SC - h.z) * 4.0f, 0.0f), 1.0f);
                    float d1 = fmaxf(n0.z * L0 + n1.z * L1 + n2.z * L2, 0.0f);
                    o.z = (d1 * 0.3f + 0.7f) * ao;
                }
                {
                    float ao = 1.0f - fminf(fmaxf((v.w * SC - h.w) * 4.0f, 0.0f), 1.0f);
                    float d1 = fmaxf(n0.w * L0 + n1.w * L1 + n2.w * L2, 0.0f);
                    o.w = (d1 * 0.3f + 0.7f) * ao;
                }
                *(float4*)(dst + base) = o;
            } else {
                *(float4*)(dst + base) = v;
            }
        }
    }
}

extern "C" void kernel_launch(void* const* d_in, const int* in_sizes, int n_in,
                              void* d_out, int out_size, void* d_ws, size_t ws_size,
                              hipStream_t stream) {
    const float* x       = (const float*)d_in[0];
    const float* normals = (const float*)d_in[1];
    float* out = (float*)d_out;
    float* ws  = (float*)d_ws;

    dim3 grid(NB, NB);
    dim3 block(512);

    // 32 iterations = 2 passes x 16 fused steps
    stencil16<0><<<grid, block, 0, stream>>>(x,  ws,  nullptr, nullptr);
    // final pass: 16 steps + fused AO/diffuse epilogue
    stencil16<1><<<grid, block, 0, stream>>>(ws, out, x, normals);
}